// Round 4
// baseline (188.675 us; speedup 1.0000x reference)
//
#include <hip/hip_runtime.h>

typedef __attribute__((ext_vector_type(8))) short s8;     // 8 bf16
typedef __attribute__((ext_vector_type(4))) float f32x4;
typedef __attribute__((ext_vector_type(16))) float f32x16;

#define GLB __attribute__((address_space(1)))
#define LDS_AS __attribute__((address_space(3)))

__device__ __forceinline__ unsigned short f2bf(float f) {
  unsigned u = __builtin_bit_cast(unsigned, f);
  return (unsigned short)((u + 0x7fffu + ((u >> 16) & 1u)) >> 16);   // RNE
}

// ---- prep 1: weight [256][128][3][3] f32 -> ws_w [tap=9][co=256][ci=128] bf16
__global__ void wprep(const float* __restrict__ w, unsigned short* __restrict__ ww) {
  int o = blockIdx.x * 256 + threadIdx.x;            // 0..294911 exact
  int ci = o & 127, co = (o >> 7) & 255, tap = o >> 15;
  ww[o] = f2bf(w[(co * 128 + ci) * 9 + tap]);
}

// ---- prep 2: x f32 NCHW -> padded NHWC bf16 [32][66][66][128]; writes own borders
__global__ void xprep(const float* __restrict__ x, unsigned int* __restrict__ xw) {
  __shared__ float tile[128][65];
  int bid = blockIdx.x;                              // b*64 + h
  int b = bid >> 6, h = bid & 63;
  int t = threadIdx.x;
  {
    int wcol = t & 63, cl = t >> 6;
    const float* src = x + ((size_t)(b * 128) * 64 + h) * 64 + wcol;
#pragma unroll
    for (int j = 0; j < 32; ++j) {
      int ci = j * 4 + cl;
      tile[ci][wcol] = src[(size_t)ci * 4096];
    }
  }
  unsigned int* dst = xw + (size_t)((b * 66 + h + 1) * 66) * 64;   // 64 dwords/pixel
  if (t < 128) {                                     // pad cols 0 / 65 of this row
    int col = (t >> 6) ? 65 : 0;
    dst[(size_t)col * 64 + (t & 63)] = 0u;
  }
  if (h == 0 || h == 63) {                           // pad rows 0 / 65 of this batch
    unsigned int* rb = xw + (size_t)(b * 66 + (h == 0 ? 0 : 65)) * 66 * 64;
    for (int j = t; j < 66 * 64; j += 256) rb[j] = 0u;
  }
  __syncthreads();
  {
    int ci2 = (t & 63) * 2, wl = t >> 6;
#pragma unroll
    for (int j = 0; j < 16; ++j) {
      int wcol = j * 4 + wl;
      unsigned p = (unsigned)f2bf(tile[ci2][wcol]) |
                   ((unsigned)f2bf(tile[ci2 + 1][wcol]) << 16);
      dst[(size_t)(wcol + 1) * 64 + (t & 63)] = p;
    }
  }
}

// ---- main: implicit GEMM. Block = 256co x 128pix (2 h-rows), 4 waves (co-split).
//      Stage ALL 128 ci once (69.6 KB LDS), then barrier-free 9-tap MFMA stream.
__global__ __launch_bounds__(256, 2) void conv_mfma(
    const unsigned short* __restrict__ xw, const unsigned short* __restrict__ ww,
    const float* __restrict__ bias, float* __restrict__ out) {
  // LDS: 272 pixels (4 pad-rows x 68 cols) x 16 units x 16B.
  // unit u of pixel q stored at position u ^ (q&15)  (bank swizzle, involution)
  __shared__ unsigned short Xl[272 * 128];           // 69,632 B
  const int tid = threadIdx.x;
  const int lane = tid & 63;
  const int l31 = lane & 31, lh = lane >> 5;
  const int mw = tid >> 6;                           // wave = co group of 64
  int bid = blockIdx.x;
  bid = (bid & 7) * 128 + (bid >> 3);                // XCD swizzle (1024%8==0)
  const int b = bid >> 5, h0 = (bid & 31) << 1;

  // ---- single-shot stage: 4352 16B units = 17 per thread, coalesced source
  {
    const char* xbase = (const char*)xw;
#pragma unroll
    for (int it = 0; it < 17; ++it) {
      int s = tid + it * 256;
      int q = s >> 4, p = s & 15;
      int u = p ^ (q & 15);
      int rr = q / 68, cc = q - rr * 68;
      if (cc > 65) cc = 65;                          // junk slots: in-bounds addr
      unsigned src = (unsigned)((b * 66 + h0 + rr) * 66 + cc) * 256u + (unsigned)u * 16u;
      __builtin_amdgcn_global_load_lds((const GLB unsigned int*)(xbase + src),
                                       (LDS_AS unsigned int*)&Xl[s * 8], 16, 0, 0);
    }
  }

  f32x16 acc[2][4];
#pragma unroll
  for (int m = 0; m < 2; ++m)
#pragma unroll
    for (int n = 0; n < 4; ++n)
#pragma unroll
      for (int e = 0; e < 16; ++e) acc[m][n][e] = 0.f;

  // A element base: co = mw*64 + m*32 + l31, ci = c*32 + kk*16 + lh*8
  const unsigned aco = (unsigned)((mw * 64 + l31) * 128 + lh * 8);
  s8 a[2][2][2];                                     // [ring slot][m][kk]

  #define ALOAD(slot, step)                                                   \
    do {                                                                      \
      const unsigned _o = aco + (unsigned)((step) >> 2) * 32768u +            \
                          (unsigned)((step) & 3) * 32u;                       \
      a[slot][0][0] = *(const s8*)(ww + _o);                                  \
      a[slot][0][1] = *(const s8*)(ww + _o + 16u);                            \
      a[slot][1][0] = *(const s8*)(ww + _o + 4096u);                          \
      a[slot][1][1] = *(const s8*)(ww + _o + 4112u);                          \
    } while (0)

  ALOAD(0, 0);
  ALOAD(1, 1);

  __syncthreads();                                   // the ONLY barrier

  const char* Xlb = (const char*)Xl;
#pragma unroll
  for (int tap = 0; tap < 9; ++tap) {
    const int kh = tap / 3, kw = tap - kh * 3;
    // per-tap B pixel bases: qt[n] = (n>>1)*68 + (n&1)*32 + l31 + kh*68 + kw
    int qt0 = l31 + (kh * 68 + kw);
    int qt[4] = {qt0, qt0 + 32, qt0 + 68, qt0 + 100};
    int bq[4], qx[4];
#pragma unroll
    for (int n = 0; n < 4; ++n) {
      bq[n] = qt[n] << 8;                            // pixel byte base (256B/pixel)
      qx[n] = ((qt[n] & 15) ^ lh);                   // xor key incl. lh bit
    }
#pragma unroll
    for (int c = 0; c < 4; ++c) {
      const int step = tap * 4 + c;
      const int slot = step & 1;
#pragma unroll
      for (int kk = 0; kk < 2; ++kk) {
#pragma unroll
        for (int n = 0; n < 4; ++n) {
          int off = bq[n] + (((c * 4 + kk * 2) ^ qx[n]) << 4);
          s8 bfr = *(const s8*)(Xlb + off);
          acc[0][n] = __builtin_amdgcn_mfma_f32_32x32x16_bf16(a[slot][0][kk], bfr, acc[0][n], 0, 0, 0);
          acc[1][n] = __builtin_amdgcn_mfma_f32_32x32x16_bf16(a[slot][1][kk], bfr, acc[1][n], 0, 0, 0);
        }
      }
      if (step + 2 < 36) ALOAD(slot, step + 2);      // distance-2 k-step prefetch
    }
  }

  // ---- epilogue: D row = (r&3) + 8*(r>>2) + 4*lh (co), col = l31 (pixel)
#pragma unroll
  for (int m = 0; m < 2; ++m)
#pragma unroll
    for (int rq = 0; rq < 4; ++rq) {
      const int cob = mw * 64 + m * 32 + 8 * rq + 4 * lh;
      const f32x4 bi = *(const f32x4*)(bias + cob);
#pragma unroll
      for (int n = 0; n < 4; ++n) {
        const int h = h0 + (n >> 1), wc = (n & 1) * 32 + l31;
        size_t base = ((size_t)(b * 256 + cob) * 64 + h) * 64 + wc;
#pragma unroll
        for (int e = 0; e < 4; ++e)
          out[base + (size_t)e * 4096] = acc[m][n][rq * 4 + e] + bi[e];
      }
    }
}

// ---- fallback (ws too small): naive f32 conv, correct but slow
__global__ void conv_naive(const float* __restrict__ x, const float* __restrict__ w,
                           const float* __restrict__ bias, float* __restrict__ out) {
  int i = blockIdx.x * 256 + threadIdx.x;
  int wc = i & 63, h = (i >> 6) & 63, co = (i >> 12) & 255, b = i >> 20;
  float s = bias[co];
  for (int ci = 0; ci < 128; ++ci)
#pragma unroll
    for (int kh = 0; kh < 3; ++kh) {
      int hh = h + kh - 1;
      if ((unsigned)hh >= 64u) continue;
#pragma unroll
      for (int kw = 0; kw < 3; ++kw) {
        int wg = wc + kw - 1;
        if ((unsigned)wg >= 64u) continue;
        s += x[((b * 128 + ci) * 64 + hh) * 64 + wg] *
             w[((co * 128 + ci) * 3 + kh) * 3 + kw];
      }
    }
  out[i] = s;
}

extern "C" void kernel_launch(void* const* d_in, const int* in_sizes, int n_in,
                              void* d_out, int out_size, void* d_ws, size_t ws_size,
                              hipStream_t stream) {
  const float* x    = (const float*)d_in[0];
  const float* w    = (const float*)d_in[1];
  const float* bias = (const float*)d_in[2];
  float* out = (float*)d_out;

  const size_t X_OFF  = 1ull << 20;                            // ws_w in first 1 MB
  const size_t XBYTES = 32ull * 66 * 66 * 128 * 2;             // 35.7 MB padded NHWC
  const size_t NEED   = X_OFF + XBYTES;

  if (ws_size >= NEED) {
    unsigned short* ww = (unsigned short*)d_ws;
    unsigned short* xq = (unsigned short*)((char*)d_ws + X_OFF);
    hipLaunchKernelGGL(wprep, dim3(1152), dim3(256), 0, stream, w, ww);
    hipLaunchKernelGGL(xprep, dim3(2048), dim3(256), 0, stream, x, (unsigned int*)xq);
    hipLaunchKernelGGL(conv_mfma, dim3(1024), dim3(256), 0, stream, xq, ww, bias, out);
  } else {
    hipLaunchKernelGGL(conv_naive, dim3(131072), dim3(256), 0, stream, x, w, bias, out);
  }
}

// Round 5
// 171.292 us; speedup vs baseline: 1.1015x; 1.1015x over previous
//
#include <hip/hip_runtime.h>

typedef __attribute__((ext_vector_type(8))) short s8;     // 8 bf16
typedef __attribute__((ext_vector_type(4))) float f32x4;
typedef __attribute__((ext_vector_type(16))) float f32x16;

#define GLB __attribute__((address_space(1)))
#define LDS_AS __attribute__((address_space(3)))

__device__ __forceinline__ unsigned short f2bf(float f) {
  unsigned u = __builtin_bit_cast(unsigned, f);
  return (unsigned short)((u + 0x7fffu + ((u >> 16) & 1u)) >> 16);   // RNE
}

// ---- prep 1: weight [256][128][3][3] f32 -> fragment-major bf16 layout:
//      ww[tap][c][cog][kk][lane][e]  (tap<9, c<4: ci/32, cog<8: co/32,
//      kk<2: ci16-half, lane=lh*32+l31 (lh: ci8-half, l31: co%32), e<8: ci)
//      => every A-fragment load in conv_mfma is lane-contiguous (1KB/wave).
__global__ void wprep(const float* __restrict__ w, unsigned short* __restrict__ ww) {
  int o = blockIdx.x * 256 + threadIdx.x;            // 0..294911 exact
  int tap = o >> 15;
  int c   = (o >> 13) & 3;
  int cog = (o >> 10) & 7;
  int kk  = (o >> 9) & 1;
  int lh  = (o >> 8) & 1;
  int l31 = (o >> 3) & 31;
  int e   = o & 7;
  int co = cog * 32 + l31;
  int ci = c * 32 + kk * 16 + lh * 8 + e;
  ww[o] = f2bf(w[(co * 128 + ci) * 9 + tap]);
}

// ---- prep 2: x f32 NCHW -> padded NHWC bf16 [32][66][66][128]; writes own borders
__global__ void xprep(const float* __restrict__ x, unsigned int* __restrict__ xw) {
  __shared__ float tile[128][65];
  int bid = blockIdx.x;                              // b*64 + h
  int b = bid >> 6, h = bid & 63;
  int t = threadIdx.x;
  {
    int wcol = t & 63, cl = t >> 6;
    const float* src = x + ((size_t)(b * 128) * 64 + h) * 64 + wcol;
#pragma unroll
    for (int j = 0; j < 32; ++j) {
      int ci = j * 4 + cl;
      tile[ci][wcol] = src[(size_t)ci * 4096];
    }
  }
  unsigned int* dst = xw + (size_t)((b * 66 + h + 1) * 66) * 64;   // 64 dwords/pixel
  if (t < 128) {                                     // pad cols 0 / 65 of this row
    int col = (t >> 6) ? 65 : 0;
    dst[(size_t)col * 64 + (t & 63)] = 0u;
  }
  if (h == 0 || h == 63) {                           // pad rows 0 / 65 of this batch
    unsigned int* rb = xw + (size_t)(b * 66 + (h == 0 ? 0 : 65)) * 66 * 64;
    for (int j = t; j < 66 * 64; j += 256) rb[j] = 0u;
  }
  __syncthreads();
  {
    int ci2 = (t & 63) * 2, wl = t >> 6;
#pragma unroll
    for (int j = 0; j < 16; ++j) {
      int wcol = j * 4 + wl;
      unsigned p = (unsigned)f2bf(tile[ci2][wcol]) |
                   ((unsigned)f2bf(tile[ci2 + 1][wcol]) << 16);
      dst[(size_t)(wcol + 1) * 64 + (t & 63)] = p;
    }
  }
}

// ---- main: implicit GEMM. Block = 256co x 128pix (2 h-rows), 4 waves (co-split).
//      Stage ALL 128 ci once (69.6 KB LDS), then barrier-free 9-tap MFMA stream.
//      A-fragments: coalesced 1KB wave-loads from fragment-major ww (L2-resident).
__global__ __launch_bounds__(256, 2) void conv_mfma(
    const unsigned short* __restrict__ xw, const unsigned short* __restrict__ ww,
    const float* __restrict__ bias, float* __restrict__ out) {
  // LDS: 272 pixels (4 pad-rows x 68 cols) x 16 units x 16B.
  // unit u of pixel q stored at position u ^ (q&15)  (bank swizzle, involution)
  __shared__ unsigned short Xl[272 * 128];           // 69,632 B
  const int tid = threadIdx.x;
  const int lane = tid & 63;
  const int l31 = lane & 31, lh = lane >> 5;
  const int mw = tid >> 6;                           // wave = co group of 64
  int bid = blockIdx.x;
  bid = (bid & 7) * 128 + (bid >> 3);                // XCD swizzle (1024%8==0)
  const int b = bid >> 5, h0 = (bid & 31) << 1;

  // ---- single-shot stage: 4352 16B units = 17 per thread, coalesced source
  {
    const char* xbase = (const char*)xw;
#pragma unroll
    for (int it = 0; it < 17; ++it) {
      int s = tid + it * 256;
      int q = s >> 4, p = s & 15;
      int u = p ^ (q & 15);
      int rr = q / 68, cc = q - rr * 68;
      if (cc > 65) cc = 65;                          // junk slots: in-bounds addr
      unsigned src = (unsigned)((b * 66 + h0 + rr) * 66 + cc) * 256u + (unsigned)u * 16u;
      __builtin_amdgcn_global_load_lds((const GLB unsigned int*)(xbase + src),
                                       (LDS_AS unsigned int*)&Xl[s * 8], 16, 0, 0);
    }
  }

  f32x16 acc[2][4];
#pragma unroll
  for (int m = 0; m < 2; ++m)
#pragma unroll
    for (int n = 0; n < 4; ++n)
#pragma unroll
      for (int e = 0; e < 16; ++e) acc[m][n][e] = 0.f;

  // A fragment base: ww + step*8192 + (mw*2+m)*1024 + kk*512 + lane*8
  s8 a[2][2][2];                                     // [ring slot][m][kk]

  #define ALOAD(slot, step)                                                   \
    do {                                                                      \
      const unsigned _b = (unsigned)(step) * 8192u + (unsigned)mw * 2048u +   \
                          (unsigned)lane * 8u;                                \
      a[slot][0][0] = *(const s8*)(ww + _b);                                  \
      a[slot][0][1] = *(const s8*)(ww + _b + 512u);                           \
      a[slot][1][0] = *(const s8*)(ww + _b + 1024u);                          \
      a[slot][1][1] = *(const s8*)(ww + _b + 1536u);                          \
    } while (0)

  ALOAD(0, 0);
  ALOAD(1, 1);

  __syncthreads();                                   // the ONLY barrier

  const char* Xlb = (const char*)Xl;
#pragma unroll
  for (int tap = 0; tap < 9; ++tap) {
    const int kh = tap / 3, kw = tap - kh * 3;
    // per-tap B pixel bases: qt[n] = (n>>1)*68 + (n&1)*32 + l31 + kh*68 + kw
    int qt0 = l31 + (kh * 68 + kw);
    int qt[4] = {qt0, qt0 + 32, qt0 + 68, qt0 + 100};
    int bq[4], qx[4];
#pragma unroll
    for (int n = 0; n < 4; ++n) {
      bq[n] = qt[n] << 8;                            // pixel byte base (256B/pixel)
      qx[n] = ((qt[n] & 15) ^ lh);                   // xor key incl. lh bit
    }
#pragma unroll
    for (int c = 0; c < 4; ++c) {
      const int step = tap * 4 + c;
      const int slot = step & 1;
#pragma unroll
      for (int kk = 0; kk < 2; ++kk) {
#pragma unroll
        for (int n = 0; n < 4; ++n) {
          int off = bq[n] + (((c * 4 + kk * 2) ^ qx[n]) << 4);
          s8 bfr = *(const s8*)(Xlb + off);
          acc[0][n] = __builtin_amdgcn_mfma_f32_32x32x16_bf16(a[slot][0][kk], bfr, acc[0][n], 0, 0, 0);
          acc[1][n] = __builtin_amdgcn_mfma_f32_32x32x16_bf16(a[slot][1][kk], bfr, acc[1][n], 0, 0, 0);
        }
      }
      if (step + 2 < 36) ALOAD(slot, step + 2);      // distance-2 k-step prefetch
    }
  }

  // ---- epilogue: D row = (r&3) + 8*(r>>2) + 4*lh (co), col = l31 (pixel)
#pragma unroll
  for (int m = 0; m < 2; ++m)
#pragma unroll
    for (int rq = 0; rq < 4; ++rq) {
      const int cob = mw * 64 + m * 32 + 8 * rq + 4 * lh;
      const f32x4 bi = *(const f32x4*)(bias + cob);
#pragma unroll
      for (int n = 0; n < 4; ++n) {
        const int h = h0 + (n >> 1), wc = (n & 1) * 32 + l31;
        size_t base = ((size_t)(b * 256 + cob) * 64 + h) * 64 + wc;
#pragma unroll
        for (int e = 0; e < 4; ++e)
          out[base + (size_t)e * 4096] = acc[m][n][rq * 4 + e] + bi[e];
      }
    }
}

// ---- fallback (ws too small): naive f32 conv, correct but slow
__global__ void conv_naive(const float* __restrict__ x, const float* __restrict__ w,
                           const float* __restrict__ bias, float* __restrict__ out) {
  int i = blockIdx.x * 256 + threadIdx.x;
  int wc = i & 63, h = (i >> 6) & 63, co = (i >> 12) & 255, b = i >> 20;
  float s = bias[co];
  for (int ci = 0; ci < 128; ++ci)
#pragma unroll
    for (int kh = 0; kh < 3; ++kh) {
      int hh = h + kh - 1;
      if ((unsigned)hh >= 64u) continue;
#pragma unroll
      for (int kw = 0; kw < 3; ++kw) {
        int wg = wc + kw - 1;
        if ((unsigned)wg >= 64u) continue;
        s += x[((b * 128 + ci) * 64 + hh) * 64 + wg] *
             w[((co * 128 + ci) * 3 + kh) * 3 + kw];
      }
    }
  out[i] = s;
}

extern "C" void kernel_launch(void* const* d_in, const int* in_sizes, int n_in,
                              void* d_out, int out_size, void* d_ws, size_t ws_size,
                              hipStream_t stream) {
  const float* x    = (const float*)d_in[0];
  const float* w    = (const float*)d_in[1];
  const float* bias = (const float*)d_in[2];
  float* out = (float*)d_out;

  const size_t X_OFF  = 1ull << 20;                            // ws_w in first 1 MB
  const size_t XBYTES = 32ull * 66 * 66 * 128 * 2;             // 35.7 MB padded NHWC
  const size_t NEED   = X_OFF + XBYTES;

  if (ws_size >= NEED) {
    unsigned short* ww = (unsigned short*)d_ws;
    unsigned short* xq = (unsigned short*)((char*)d_ws + X_OFF);
    hipLaunchKernelGGL(wprep, dim3(1152), dim3(256), 0, stream, w, ww);
    hipLaunchKernelGGL(xprep, dim3(2048), dim3(256), 0, stream, x, (unsigned int*)xq);
    hipLaunchKernelGGL(conv_mfma, dim3(1024), dim3(256), 0, stream, xq, ww, bias, out);
  } else {
    hipLaunchKernelGGL(conv_naive, dim3(131072), dim3(256), 0, stream, x, w, bias, out);
  }
}

// Round 6
// 113.154 us; speedup vs baseline: 1.6674x; 1.5138x over previous
//
#include <hip/hip_runtime.h>

typedef __attribute__((ext_vector_type(8))) short s8;     // 8 bf16
typedef __attribute__((ext_vector_type(4))) float f32x4;
typedef __attribute__((ext_vector_type(16))) float f32x16;

#define GLB __attribute__((address_space(1)))
#define LDS_AS __attribute__((address_space(3)))

__device__ __forceinline__ unsigned short f2bf(float f) {
  unsigned u = __builtin_bit_cast(unsigned, f);
  return (unsigned short)((u + 0x7fffu + ((u >> 16) & 1u)) >> 16);   // RNE
}

// ---- prep 1: weight [256][128][3][3] f32 -> fragment-major bf16 layout:
//      ww[tap][c][cog][kk][lane][e]  (tap<9, c<4: ci/32, cog<8: co/32,
//      kk<2: ci16-half, lane=lh*32+l31 (lh: ci8-half, l31: co%32), e<8: ci)
//      => every A-fragment load in conv_mfma is lane-contiguous (1KB/wave).
__global__ void wprep(const float* __restrict__ w, unsigned short* __restrict__ ww) {
  int o = blockIdx.x * 256 + threadIdx.x;            // 0..294911 exact
  int tap = o >> 15;
  int c   = (o >> 13) & 3;
  int cog = (o >> 10) & 7;
  int kk  = (o >> 9) & 1;
  int lh  = (o >> 8) & 1;
  int l31 = (o >> 3) & 31;
  int e   = o & 7;
  int co = cog * 32 + l31;
  int ci = c * 32 + kk * 16 + lh * 8 + e;
  ww[o] = f2bf(w[(co * 128 + ci) * 9 + tap]);
}

// ---- prep 2: x f32 NCHW -> padded NHWC bf16 [32][66][66][128]; writes own borders
__global__ void xprep(const float* __restrict__ x, unsigned int* __restrict__ xw) {
  __shared__ float tile[128][65];
  int bid = blockIdx.x;                              // b*64 + h
  int b = bid >> 6, h = bid & 63;
  int t = threadIdx.x;
  {
    int wcol = t & 63, cl = t >> 6;
    const float* src = x + ((size_t)(b * 128) * 64 + h) * 64 + wcol;
#pragma unroll
    for (int j = 0; j < 32; ++j) {
      int ci = j * 4 + cl;
      tile[ci][wcol] = src[(size_t)ci * 4096];
    }
  }
  unsigned int* dst = xw + (size_t)((b * 66 + h + 1) * 66) * 64;   // 64 dwords/pixel
  if (t < 128) {                                     // pad cols 0 / 65 of this row
    int col = (t >> 6) ? 65 : 0;
    dst[(size_t)col * 64 + (t & 63)] = 0u;
  }
  if (h == 0 || h == 63) {                           // pad rows 0 / 65 of this batch
    unsigned int* rb = xw + (size_t)(b * 66 + (h == 0 ? 0 : 65)) * 66 * 64;
    for (int j = t; j < 66 * 64; j += 256) rb[j] = 0u;
  }
  __syncthreads();
  {
    int ci2 = (t & 63) * 2, wl = t >> 6;
#pragma unroll
    for (int j = 0; j < 16; ++j) {
      int wcol = j * 4 + wl;
      unsigned p = (unsigned)f2bf(tile[ci2][wcol]) |
                   ((unsigned)f2bf(tile[ci2 + 1][wcol]) << 16);
      dst[(size_t)(wcol + 1) * 64 + (t & 63)] = p;
    }
  }
}

// ---- main: implicit GEMM. Block = 256co x 64pix (1 h-row), 4 waves (co-split),
//      wave = 64co x 64pix (acc 64 regs -> 3 blocks/CU, 12 waves/CU).
//      Stage 3 rows x 68 cols x 128ci once (52.2 KB), barrier-free MFMA stream.
__global__ __launch_bounds__(256, 3) void conv_mfma(
    const unsigned short* __restrict__ xw, const unsigned short* __restrict__ ww,
    const float* __restrict__ bias, float* __restrict__ out) {
  // LDS: 204 pixels (3 pad-rows x 68 cols) x 16 units x 16B.
  // unit u of pixel q stored at position u ^ (q&15)  (bank swizzle, involution)
  __shared__ unsigned short Xl[204 * 128];           // 52,224 B
  const int tid = threadIdx.x;
  const int lane = tid & 63;
  const int l31 = lane & 31, lh = lane >> 5;
  const int mw = tid >> 6;                           // wave = co group of 64
  int bid = blockIdx.x;
  bid = (bid & 7) * 256 + (bid >> 3);                // XCD swizzle (2048%8==0)
  const int b = bid >> 6, h0 = bid & 63;

  // ---- single-shot stage: 3264 16B units, coalesced source, linear LDS dest
  {
    const char* xbase = (const char*)xw;
#pragma unroll
    for (int it = 0; it < 13; ++it) {
      int s = tid + it * 256;
      if (s < 3264) {
        int q = s >> 4, p = s & 15;
        int u = p ^ (q & 15);
        int rr = q / 68, cc = q - rr * 68;
        if (cc > 65) cc = 65;                        // junk slots: in-bounds addr
        unsigned src = (unsigned)((b * 66 + h0 + rr) * 66 + cc) * 256u + (unsigned)u * 16u;
        __builtin_amdgcn_global_load_lds((const GLB unsigned int*)(xbase + src),
                                         (LDS_AS unsigned int*)&Xl[s * 8], 16, 0, 0);
      }
    }
  }

  f32x16 acc[2][2];
#pragma unroll
  for (int m = 0; m < 2; ++m)
#pragma unroll
    for (int n = 0; n < 2; ++n)
#pragma unroll
      for (int e = 0; e < 16; ++e) acc[m][n][e] = 0.f;

  // A fragment base: ww + step*8192 + mw*2048 + m*1024 + kk*512 + lane*8
  s8 a[2][2][2];                                     // [ring slot][m][kk]

  #define ALOAD(slot, step)                                                   \
    do {                                                                      \
      const unsigned _b = (unsigned)(step) * 8192u + (unsigned)mw * 2048u +   \
                          (unsigned)lane * 8u;                                \
      a[slot][0][0] = *(const s8*)(ww + _b);                                  \
      a[slot][0][1] = *(const s8*)(ww + _b + 512u);                           \
      a[slot][1][0] = *(const s8*)(ww + _b + 1024u);                          \
      a[slot][1][1] = *(const s8*)(ww + _b + 1536u);                          \
    } while (0)

  ALOAD(0, 0);
  ALOAD(1, 1);

  __syncthreads();                                   // the ONLY barrier

  const char* Xlb = (const char*)Xl;
#pragma unroll
  for (int tap = 0; tap < 9; ++tap) {
    const int kh = tap / 3, kw = tap - kh * 3;
    // B pixel bases: pixel w = n*32 + l31 -> slot q = kh*68 + (kw + w)
    const int qt0 = kh * 68 + kw + l31;
    int bq[2] = {qt0 << 8, (qt0 + 32) << 8};
    int qx[2] = {(qt0 & 15) ^ lh, ((qt0 + 32) & 15) ^ lh};
#pragma unroll
    for (int c = 0; c < 4; ++c) {
      const int step = tap * 4 + c;
      const int slot = step & 1;
#pragma unroll
      for (int kk = 0; kk < 2; ++kk) {
        const int usel = c * 4 + kk * 2;
#pragma unroll
        for (int n = 0; n < 2; ++n) {
          s8 bfr = *(const s8*)(Xlb + bq[n] + ((usel ^ qx[n]) << 4));
          acc[0][n] = __builtin_amdgcn_mfma_f32_32x32x16_bf16(a[slot][0][kk], bfr, acc[0][n], 0, 0, 0);
          acc[1][n] = __builtin_amdgcn_mfma_f32_32x32x16_bf16(a[slot][1][kk], bfr, acc[1][n], 0, 0, 0);
        }
      }
      if (step + 2 < 36) ALOAD(slot, step + 2);      // distance-2 k-step prefetch
    }
  }

  // ---- epilogue: D row = (r&3) + 8*(r>>2) + 4*lh (co), col = l31 (pixel)
#pragma unroll
  for (int m = 0; m < 2; ++m)
#pragma unroll
    for (int rq = 0; rq < 4; ++rq) {
      const int cob = mw * 64 + m * 32 + 8 * rq + 4 * lh;
      const f32x4 bi = *(const f32x4*)(bias + cob);
#pragma unroll
      for (int n = 0; n < 2; ++n) {
        const int wc = n * 32 + l31;
        size_t base = ((size_t)(b * 256 + cob) * 64 + h0) * 64 + wc;
#pragma unroll
        for (int e = 0; e < 4; ++e)
          out[base + (size_t)e * 4096] = acc[m][n][rq * 4 + e] + bi[e];
      }
    }
}

// ---- fallback (ws too small): naive f32 conv, correct but slow
__global__ void conv_naive(const float* __restrict__ x, const float* __restrict__ w,
                           const float* __restrict__ bias, float* __restrict__ out) {
  int i = blockIdx.x * 256 + threadIdx.x;
  int wc = i & 63, h = (i >> 6) & 63, co = (i >> 12) & 255, b = i >> 20;
  float s = bias[co];
  for (int ci = 0; ci < 128; ++ci)
#pragma unroll
    for (int kh = 0; kh < 3; ++kh) {
      int hh = h + kh - 1;
      if ((unsigned)hh >= 64u) continue;
#pragma unroll
      for (int kw = 0; kw < 3; ++kw) {
        int wg = wc + kw - 1;
        if ((unsigned)wg >= 64u) continue;
        s += x[((b * 128 + ci) * 64 + hh) * 64 + wg] *
             w[((co * 128 + ci) * 3 + kh) * 3 + kw];
      }
    }
  out[i] = s;
}

extern "C" void kernel_launch(void* const* d_in, const int* in_sizes, int n_in,
                              void* d_out, int out_size, void* d_ws, size_t ws_size,
                              hipStream_t stream) {
  const float* x    = (const float*)d_in[0];
  const float* w    = (const float*)d_in[1];
  const float* bias = (const float*)d_in[2];
  float* out = (float*)d_out;

  const size_t X_OFF  = 1ull << 20;                            // ws_w in first 1 MB
  const size_t XBYTES = 32ull * 66 * 66 * 128 * 2;             // 35.7 MB padded NHWC
  const size_t NEED   = X_OFF + XBYTES;

  if (ws_size >= NEED) {
    unsigned short* ww = (unsigned short*)d_ws;
    unsigned short* xq = (unsigned short*)((char*)d_ws + X_OFF);
    hipLaunchKernelGGL(wprep, dim3(1152), dim3(256), 0, stream, w, ww);
    hipLaunchKernelGGL(xprep, dim3(2048), dim3(256), 0, stream, x, (unsigned int*)xq);
    hipLaunchKernelGGL(conv_mfma, dim3(2048), dim3(256), 0, stream, xq, ww, bias, out);
  } else {
    hipLaunchKernelGGL(conv_naive, dim3(131072), dim3(256), 0, stream, x, w, bias, out);
  }
}

// Round 7
// 113.124 us; speedup vs baseline: 1.6679x; 1.0003x over previous
//
#include <hip/hip_runtime.h>

typedef __attribute__((ext_vector_type(8))) short s8;     // 8 bf16
typedef __attribute__((ext_vector_type(4))) float f32x4;
typedef __attribute__((ext_vector_type(16))) float f32x16;

#define GLB __attribute__((address_space(1)))
#define LDS_AS __attribute__((address_space(3)))

__device__ __forceinline__ unsigned short f2bf(float f) {
  unsigned u = __builtin_bit_cast(unsigned, f);
  return (unsigned short)((u + 0x7fffu + ((u >> 16) & 1u)) >> 16);   // RNE
}

// ---- prep 1: weight [256][128][3][3] f32 -> fragment-major bf16 layout:
//      ww[tap][c][cog][kk][lane][e]  (tap<9, c<4: ci/32, cog<8: co/32,
//      kk<2: ci16-half, lane=lh*32+l31 (lh: ci8-half, l31: co%32), e<8: ci)
//      => every A-fragment load in conv_mfma is lane-contiguous (1KB/wave).
__global__ void wprep(const float* __restrict__ w, unsigned short* __restrict__ ww) {
  int o = blockIdx.x * 256 + threadIdx.x;            // 0..294911 exact
  int tap = o >> 15;
  int c   = (o >> 13) & 3;
  int cog = (o >> 10) & 7;
  int kk  = (o >> 9) & 1;
  int lh  = (o >> 8) & 1;
  int l31 = (o >> 3) & 31;
  int e   = o & 7;
  int co = cog * 32 + l31;
  int ci = c * 32 + kk * 16 + lh * 8 + e;
  ww[o] = f2bf(w[(co * 128 + ci) * 9 + tap]);
}

// ---- prep 2: x f32 NCHW -> padded NHWC bf16 [32][66][66][128]; writes own borders
__global__ void xprep(const float* __restrict__ x, unsigned int* __restrict__ xw) {
  __shared__ float tile[128][65];
  int bid = blockIdx.x;                              // b*64 + h
  int b = bid >> 6, h = bid & 63;
  int t = threadIdx.x;
  {
    int wcol = t & 63, cl = t >> 6;
    const float* src = x + ((size_t)(b * 128) * 64 + h) * 64 + wcol;
#pragma unroll
    for (int j = 0; j < 32; ++j) {
      int ci = j * 4 + cl;
      tile[ci][wcol] = src[(size_t)ci * 4096];
    }
  }
  unsigned int* dst = xw + (size_t)((b * 66 + h + 1) * 66) * 64;   // 64 dwords/pixel
  if (t < 128) {                                     // pad cols 0 / 65 of this row
    int col = (t >> 6) ? 65 : 0;
    dst[(size_t)col * 64 + (t & 63)] = 0u;
  }
  if (h == 0 || h == 63) {                           // pad rows 0 / 65 of this batch
    unsigned int* rb = xw + (size_t)(b * 66 + (h == 0 ? 0 : 65)) * 66 * 64;
    for (int j = t; j < 66 * 64; j += 256) rb[j] = 0u;
  }
  __syncthreads();
  {
    int ci2 = (t & 63) * 2, wl = t >> 6;
#pragma unroll
    for (int j = 0; j < 16; ++j) {
      int wcol = j * 4 + wl;
      unsigned p = (unsigned)f2bf(tile[ci2][wcol]) |
                   ((unsigned)f2bf(tile[ci2 + 1][wcol]) << 16);
      dst[(size_t)(wcol + 1) * 64 + (t & 63)] = p;
    }
  }
}

// ---- main: implicit GEMM. Block = 256co x 64pix (1 h-row), 4 waves (co-split),
//      wave = 64co x 64pix. Stage 3 rows x 68 x 128ci once (52.2 KB), then a
//      barrier-free MFMA stream with step-level A and B register pipelines.
__global__ __launch_bounds__(256, 3) void conv_mfma(
    const unsigned short* __restrict__ xw, const unsigned short* __restrict__ ww,
    const float* __restrict__ bias, float* __restrict__ out) {
  // LDS: 204 pixels (3 pad-rows x 68 cols) x 16 units x 16B.
  // unit u of pixel q stored at position u ^ (q&15)  (bank swizzle, involution)
  __shared__ unsigned short Xl[204 * 128];           // 52,224 B
  const int tid = threadIdx.x;
  const int lane = tid & 63;
  const int l31 = lane & 31, lh = lane >> 5;
  const int mw = tid >> 6;                           // wave = co group of 64
  int bid = blockIdx.x;
  bid = (bid & 7) * 256 + (bid >> 3);                // XCD swizzle (2048%8==0)
  const int b = bid >> 6, h0 = bid & 63;

  // ---- single-shot stage: 3264 16B units, coalesced source, linear LDS dest
  {
    const char* xbase = (const char*)xw;
#pragma unroll
    for (int it = 0; it < 13; ++it) {
      int s = tid + it * 256;
      if (s < 3264) {
        int q = s >> 4, p = s & 15;
        int u = p ^ (q & 15);
        int rr = q / 68, cc = q - rr * 68;
        if (cc > 65) cc = 65;                        // junk slots: in-bounds addr
        unsigned src = (unsigned)((b * 66 + h0 + rr) * 66 + cc) * 256u + (unsigned)u * 16u;
        __builtin_amdgcn_global_load_lds((const GLB unsigned int*)(xbase + src),
                                         (LDS_AS unsigned int*)&Xl[s * 8], 16, 0, 0);
      }
    }
  }

  f32x16 acc[2][2];
#pragma unroll
  for (int m = 0; m < 2; ++m)
#pragma unroll
    for (int n = 0; n < 2; ++n)
#pragma unroll
      for (int e = 0; e < 16; ++e) acc[m][n][e] = 0.f;

  s8 a[2][2][2];                                     // [ring slot][m][kk]
  s8 bfr[2][2][2];                                   // [ring slot][n][kk]

  // A fragment base: ww + step*8192 + mw*2048 + m*1024 + kk*512 + lane*8
  #define ALOAD(slot, step)                                                   \
    do {                                                                      \
      const unsigned _b = (unsigned)(step) * 8192u + (unsigned)mw * 2048u +   \
                          (unsigned)lane * 8u;                                \
      a[slot][0][0] = *(const s8*)(ww + _b);                                  \
      a[slot][0][1] = *(const s8*)(ww + _b + 512u);                           \
      a[slot][1][0] = *(const s8*)(ww + _b + 1024u);                          \
      a[slot][1][1] = *(const s8*)(ww + _b + 1536u);                          \
    } while (0)

  // B fragments for step (tap,c) from swizzled LDS
  #define BLOAD(slot, step)                                                   \
    do {                                                                      \
      const int _tap = (step) >> 2, _c = (step) & 3;                          \
      const int _kh = _tap / 3, _kw = _tap - _kh * 3;                         \
      const int _qt0 = _kh * 68 + _kw + l31;                                  \
      const int _qt1 = _qt0 + 32;                                             \
      const int _b0 = _qt0 << 8, _b1 = _qt1 << 8;                             \
      const int _x0 = (_qt0 & 15) ^ lh, _x1 = (_qt1 & 15) ^ lh;               \
      bfr[slot][0][0] = *(const s8*)(Xlb + _b0 + (((_c * 4) ^ _x0) << 4));    \
      bfr[slot][1][0] = *(const s8*)(Xlb + _b1 + (((_c * 4) ^ _x1) << 4));    \
      bfr[slot][0][1] = *(const s8*)(Xlb + _b0 + (((_c * 4 + 2) ^ _x0) << 4));\
      bfr[slot][1][1] = *(const s8*)(Xlb + _b1 + (((_c * 4 + 2) ^ _x1) << 4));\
    } while (0)

  const char* Xlb = (const char*)Xl;

  ALOAD(0, 0);
  ALOAD(1, 1);

  __syncthreads();                                   // staged x ready (the ONLY barrier)

  BLOAD(0, 0);
  BLOAD(1, 1);

#pragma unroll
  for (int s = 0; s < 36; ++s) {
    const int sl = s & 1;
    __builtin_amdgcn_s_setprio(1);
#pragma unroll
    for (int kk = 0; kk < 2; ++kk) {
      acc[0][0] = __builtin_amdgcn_mfma_f32_32x32x16_bf16(a[sl][0][kk], bfr[sl][0][kk], acc[0][0], 0, 0, 0);
      acc[1][0] = __builtin_amdgcn_mfma_f32_32x32x16_bf16(a[sl][1][kk], bfr[sl][0][kk], acc[1][0], 0, 0, 0);
      acc[0][1] = __builtin_amdgcn_mfma_f32_32x32x16_bf16(a[sl][0][kk], bfr[sl][1][kk], acc[0][1], 0, 0, 0);
      acc[1][1] = __builtin_amdgcn_mfma_f32_32x32x16_bf16(a[sl][1][kk], bfr[sl][1][kk], acc[1][1], 0, 0, 0);
    }
    __builtin_amdgcn_s_setprio(0);
    if (s + 2 < 36) {                                // refill ring for step s+2:
      BLOAD(sl, s + 2);                              // overlaps step s+1's MFMAs
      ALOAD(sl, s + 2);
    }
  }

  // ---- epilogue: D row = (r&3) + 8*(r>>2) + 4*lh (co), col = l31 (pixel)
#pragma unroll
  for (int m = 0; m < 2; ++m)
#pragma unroll
    for (int rq = 0; rq < 4; ++rq) {
      const int cob = mw * 64 + m * 32 + 8 * rq + 4 * lh;
      const f32x4 bi = *(const f32x4*)(bias + cob);
#pragma unroll
      for (int n = 0; n < 2; ++n) {
        const int wc = n * 32 + l31;
        size_t base = ((size_t)(b * 256 + cob) * 64 + h0) * 64 + wc;
#pragma unroll
        for (int e = 0; e < 4; ++e)
          out[base + (size_t)e * 4096] = acc[m][n][rq * 4 + e] + bi[e];
      }
    }
}

// ---- fallback (ws too small): naive f32 conv, correct but slow
__global__ void conv_naive(const float* __restrict__ x, const float* __restrict__ w,
                           const float* __restrict__ bias, float* __restrict__ out) {
  int i = blockIdx.x * 256 + threadIdx.x;
  int wc = i & 63, h = (i >> 6) & 63, co = (i >> 12) & 255, b = i >> 20;
  float s = bias[co];
  for (int ci = 0; ci < 128; ++ci)
#pragma unroll
    for (int kh = 0; kh < 3; ++kh) {
      int hh = h + kh - 1;
      if ((unsigned)hh >= 64u) continue;
#pragma unroll
      for (int kw = 0; kw < 3; ++kw) {
        int wg = wc + kw - 1;
        if ((unsigned)wg >= 64u) continue;
        s += x[((b * 128 + ci) * 64 + hh) * 64 + wg] *
             w[((co * 128 + ci) * 3 + kh) * 3 + kw];
      }
    }
  out[i] = s;
}

extern "C" void kernel_launch(void* const* d_in, const int* in_sizes, int n_in,
                              void* d_out, int out_size, void* d_ws, size_t ws_size,
                              hipStream_t stream) {
  const float* x    = (const float*)d_in[0];
  const float* w    = (const float*)d_in[1];
  const float* bias = (const float*)d_in[2];
  float* out = (float*)d_out;

  const size_t X_OFF  = 1ull << 20;                            // ws_w in first 1 MB
  const size_t XBYTES = 32ull * 66 * 66 * 128 * 2;             // 35.7 MB padded NHWC
  const size_t NEED   = X_OFF + XBYTES;

  if (ws_size >= NEED) {
    unsigned short* ww = (unsigned short*)d_ws;
    unsigned short* xq = (unsigned short*)((char*)d_ws + X_OFF);
    hipLaunchKernelGGL(wprep, dim3(1152), dim3(256), 0, stream, w, ww);
    hipLaunchKernelGGL(xprep, dim3(2048), dim3(256), 0, stream, x, (unsigned int*)xq);
    hipLaunchKernelGGL(conv_mfma, dim3(2048), dim3(256), 0, stream, xq, ww, bias, out);
  } else {
    hipLaunchKernelGGL(conv_naive, dim3(131072), dim3(256), 0, stream, x, w, bias, out);
  }
}

// Round 8
// 108.049 us; speedup vs baseline: 1.7462x; 1.0470x over previous
//
#include <hip/hip_runtime.h>

typedef __attribute__((ext_vector_type(4))) int   v4i;
typedef __attribute__((ext_vector_type(8))) short s8;     // 8 bf16
typedef __attribute__((ext_vector_type(4))) float f32x4;
typedef __attribute__((ext_vector_type(16))) float f32x16;

#define GLB __attribute__((address_space(1)))
#define LDS_AS __attribute__((address_space(3)))

__device__ __forceinline__ unsigned short f2bf(float f) {
  unsigned u = __builtin_bit_cast(unsigned, f);
  return (unsigned short)((u + 0x7fffu + ((u >> 16) & 1u)) >> 16);   // RNE
}

// ---- prep 1: weight [256][128][3][3] f32 -> fragment-major bf16 layout:
//      ww[tap][c][cog][kk][lane][e]  => every A-fragment load is lane-contiguous.
__global__ void wprep(const float* __restrict__ w, unsigned short* __restrict__ ww) {
  int o = blockIdx.x * 256 + threadIdx.x;            // 0..294911 exact
  int tap = o >> 15;
  int c   = (o >> 13) & 3;
  int cog = (o >> 10) & 7;
  int kk  = (o >> 9) & 1;
  int lh  = (o >> 8) & 1;
  int l31 = (o >> 3) & 31;
  int e   = o & 7;
  int co = cog * 32 + l31;
  int ci = c * 32 + kk * 16 + lh * 8 + e;
  ww[o] = f2bf(w[(co * 128 + ci) * 9 + tap]);
}

// ---- prep 2: x f32 NCHW -> padded NHWC bf16 [32][66][66][128]; writes own borders
__global__ void xprep(const float* __restrict__ x, unsigned int* __restrict__ xw) {
  __shared__ float tile[128][65];
  int bid = blockIdx.x;                              // b*64 + h
  int b = bid >> 6, h = bid & 63;
  int t = threadIdx.x;
  {
    int wcol = t & 63, cl = t >> 6;
    const float* src = x + ((size_t)(b * 128) * 64 + h) * 64 + wcol;
#pragma unroll
    for (int j = 0; j < 32; ++j) {
      int ci = j * 4 + cl;
      tile[ci][wcol] = src[(size_t)ci * 4096];
    }
  }
  unsigned int* dst = xw + (size_t)((b * 66 + h + 1) * 66) * 64;   // 64 dwords/pixel
  if (t < 128) {                                     // pad cols 0 / 65 of this row
    int col = (t >> 6) ? 65 : 0;
    dst[(size_t)col * 64 + (t & 63)] = 0u;
  }
  if (h == 0 || h == 63) {                           // pad rows 0 / 65 of this batch
    unsigned int* rb = xw + (size_t)(b * 66 + (h == 0 ? 0 : 65)) * 66 * 64;
    for (int j = t; j < 66 * 64; j += 256) rb[j] = 0u;
  }
  __syncthreads();
  {
    int ci2 = (t & 63) * 2, wl = t >> 6;
#pragma unroll
    for (int j = 0; j < 16; ++j) {
      int wcol = j * 4 + wl;
      unsigned p = (unsigned)f2bf(tile[ci2][wcol]) |
                   ((unsigned)f2bf(tile[ci2 + 1][wcol]) << 16);
      dst[(size_t)(wcol + 1) * 64 + (t & 63)] = p;
    }
  }
}

// ---- main: implicit GEMM. Block = 256co x 64pix (1 h-row), 4 waves (co-split),
//      wave = 64co x 64pix. Stage 3 rows x 68 x 128ci once (52.2 KB), then a
//      barrier-free MFMA stream with an UNCOLLAPSIBLE asm A-ring (counted vmcnt).
__global__ __launch_bounds__(256, 3) void conv_mfma(
    const unsigned short* __restrict__ xw, const unsigned short* __restrict__ ww,
    const float* __restrict__ bias, float* __restrict__ out) {
  // LDS: 204 pixels (3 pad-rows x 68 cols) x 16 units x 16B.
  // unit u of pixel q stored at position u ^ (q&15)  (bank swizzle, involution)
  __shared__ unsigned short Xl[204 * 128];           // 52,224 B
  const int tid = threadIdx.x;
  const int lane = tid & 63;
  const int l31 = lane & 31, lh = lane >> 5;
  const int mw = tid >> 6;                           // wave = co group of 64
  int bid = blockIdx.x;
  bid = (bid & 7) * 256 + (bid >> 3);                // XCD swizzle (2048%8==0)
  const int b = bid >> 6, h0 = bid & 63;

  // ---- single-shot stage: 3264 16B units, coalesced source, linear LDS dest
  {
    const char* xbase = (const char*)xw;
#pragma unroll
    for (int it = 0; it < 13; ++it) {
      int s = tid + it * 256;
      if (s < 3264) {
        int q = s >> 4, p = s & 15;
        int u = p ^ (q & 15);
        int rr = q / 68, cc = q - rr * 68;
        if (cc > 65) cc = 65;                        // junk slots: in-bounds addr
        unsigned src = (unsigned)((b * 66 + h0 + rr) * 66 + cc) * 256u + (unsigned)u * 16u;
        __builtin_amdgcn_global_load_lds((const GLB unsigned int*)(xbase + src),
                                         (LDS_AS unsigned int*)&Xl[s * 8], 16, 0, 0);
      }
    }
  }

  f32x16 acc[2][2];
#pragma unroll
  for (int m = 0; m < 2; ++m)
#pragma unroll
    for (int n = 0; n < 2; ++n)
#pragma unroll
      for (int e = 0; e < 16; ++e) acc[m][n][e] = 0.f;

  // A ring: 3 slots x 4 fragments (j = m*2+kk), issued 2 steps ahead via asm.
  v4i areg[3][4];
  const unsigned abyte = (unsigned)(mw * 4096 + lane * 16);   // byte base in step

  // step-relative byte base = step*16384 + abyte; frag imm = {0,1024,2048,3072}
  #define ALOAD_ASM(slot, step)                                               \
    do {                                                                      \
      unsigned _wo = (unsigned)(step) * 16384u + abyte;                       \
      asm volatile("global_load_dwordx4 %0, %1, %2 offset:0"                  \
                   : "=v"(areg[slot][0]) : "v"(_wo), "s"(ww));                \
      asm volatile("global_load_dwordx4 %0, %1, %2 offset:1024"               \
                   : "=v"(areg[slot][1]) : "v"(_wo), "s"(ww));                \
      asm volatile("global_load_dwordx4 %0, %1, %2 offset:2048"               \
                   : "=v"(areg[slot][2]) : "v"(_wo), "s"(ww));                \
      asm volatile("global_load_dwordx4 %0, %1, %2 offset:3072"               \
                   : "=v"(areg[slot][3]) : "v"(_wo), "s"(ww));                \
    } while (0)

  const char* Xlb = (const char*)Xl;

  __syncthreads();                  // staged x ready; drains staging vmcnt to 0

  ALOAD_ASM(0, 0);                  // prime ring: A(0), A(1) in flight
  ALOAD_ASM(1, 1);

#pragma unroll
  for (int s = 0; s < 36; ++s) {
    if (s < 34) ALOAD_ASM((s + 2) % 3, s + 2);       // issue A(s+2): 8 in flight

    // B fragments for step s from swizzled LDS (compiler-scheduled, lgkm-tracked)
    const int _tap = s >> 2, _c = s & 3;
    const int _kh = _tap / 3, _kw = _tap - _kh * 3;
    const int _qt0 = _kh * 68 + _kw + l31;
    const int _qt1 = _qt0 + 32;
    const int _b0 = _qt0 << 8, _b1 = _qt1 << 8;
    const int _x0 = (_qt0 & 15) ^ lh, _x1 = (_qt1 & 15) ^ lh;
    s8 b00 = *(const s8*)(Xlb + _b0 + (((_c * 4) ^ _x0) << 4));
    s8 b10 = *(const s8*)(Xlb + _b1 + (((_c * 4) ^ _x1) << 4));
    s8 b01 = *(const s8*)(Xlb + _b0 + (((_c * 4 + 2) ^ _x0) << 4));
    s8 b11 = *(const s8*)(Xlb + _b1 + (((_c * 4 + 2) ^ _x1) << 4));

    // counted wait: A(s) landed; A(s+1), A(s+2) stay in flight (never drain to 0)
    if (s < 34)      asm volatile("s_waitcnt vmcnt(8)" ::: "memory");
    else if (s == 34) asm volatile("s_waitcnt vmcnt(4)" ::: "memory");
    else              asm volatile("s_waitcnt vmcnt(0)" ::: "memory");
    __builtin_amdgcn_sched_barrier(0);               // rule #18: MFMAs stay below

    const int cs = s % 3;
    __builtin_amdgcn_s_setprio(1);
    acc[0][0] = __builtin_amdgcn_mfma_f32_32x32x16_bf16(__builtin_bit_cast(s8, areg[cs][0]), b00, acc[0][0], 0, 0, 0);
    acc[1][0] = __builtin_amdgcn_mfma_f32_32x32x16_bf16(__builtin_bit_cast(s8, areg[cs][2]), b00, acc[1][0], 0, 0, 0);
    acc[0][1] = __builtin_amdgcn_mfma_f32_32x32x16_bf16(__builtin_bit_cast(s8, areg[cs][0]), b10, acc[0][1], 0, 0, 0);
    acc[1][1] = __builtin_amdgcn_mfma_f32_32x32x16_bf16(__builtin_bit_cast(s8, areg[cs][2]), b10, acc[1][1], 0, 0, 0);
    acc[0][0] = __builtin_amdgcn_mfma_f32_32x32x16_bf16(__builtin_bit_cast(s8, areg[cs][1]), b01, acc[0][0], 0, 0, 0);
    acc[1][0] = __builtin_amdgcn_mfma_f32_32x32x16_bf16(__builtin_bit_cast(s8, areg[cs][3]), b01, acc[1][0], 0, 0, 0);
    acc[0][1] = __builtin_amdgcn_mfma_f32_32x32x16_bf16(__builtin_bit_cast(s8, areg[cs][1]), b11, acc[0][1], 0, 0, 0);
    acc[1][1] = __builtin_amdgcn_mfma_f32_32x32x16_bf16(__builtin_bit_cast(s8, areg[cs][3]), b11, acc[1][1], 0, 0, 0);
    __builtin_amdgcn_s_setprio(0);
  }

  // ---- epilogue: D row = (r&3) + 8*(r>>2) + 4*lh (co), col = l31 (pixel)
#pragma unroll
  for (int m = 0; m < 2; ++m)
#pragma unroll
    for (int rq = 0; rq < 4; ++rq) {
      const int cob = mw * 64 + m * 32 + 8 * rq + 4 * lh;
      const f32x4 bi = *(const f32x4*)(bias + cob);
#pragma unroll
      for (int n = 0; n < 2; ++n) {
        const int wc = n * 32 + l31;
        size_t base = ((size_t)(b * 256 + cob) * 64 + h0) * 64 + wc;
#pragma unroll
        for (int e = 0; e < 4; ++e)
          out[base + (size_t)e * 4096] = acc[m][n][rq * 4 + e] + bi[e];
      }
    }
}

// ---- fallback (ws too small): naive f32 conv, correct but slow
__global__ void conv_naive(const float* __restrict__ x, const float* __restrict__ w,
                           const float* __restrict__ bias, float* __restrict__ out) {
  int i = blockIdx.x * 256 + threadIdx.x;
  int wc = i & 63, h = (i >> 6) & 63, co = (i >> 12) & 255, b = i >> 20;
  float s = bias[co];
  for (int ci = 0; ci < 128; ++ci)
#pragma unroll
    for (int kh = 0; kh < 3; ++kh) {
      int hh = h + kh - 1;
      if ((unsigned)hh >= 64u) continue;
#pragma unroll
      for (int kw = 0; kw < 3; ++kw) {
        int wg = wc + kw - 1;
        if ((unsigned)wg >= 64u) continue;
        s += x[((b * 128 + ci) * 64 + hh) * 64 + wg] *
             w[((co * 128 + ci) * 3 + kh) * 3 + kw];
      }
    }
  out[i] = s;
}

extern "C" void kernel_launch(void* const* d_in, const int* in_sizes, int n_in,
                              void* d_out, int out_size, void* d_ws, size_t ws_size,
                              hipStream_t stream) {
  const float* x    = (const float*)d_in[0];
  const float* w    = (const float*)d_in[1];
  const float* bias = (const float*)d_in[2];
  float* out = (float*)d_out;

  const size_t X_OFF  = 1ull << 20;                            // ws_w in first 1 MB
  const size_t XBYTES = 32ull * 66 * 66 * 128 * 2;             // 35.7 MB padded NHWC
  const size_t NEED   = X_OFF + XBYTES;

  if (ws_size >= NEED) {
    unsigned short* ww = (unsigned short*)d_ws;
    unsigned short* xq = (unsigned short*)((char*)d_ws + X_OFF);
    hipLaunchKernelGGL(wprep, dim3(1152), dim3(256), 0, stream, w, ww);
    hipLaunchKernelGGL(xprep, dim3(2048), dim3(256), 0, stream, x, (unsigned int*)xq);
    hipLaunchKernelGGL(conv_mfma, dim3(2048), dim3(256), 0, stream, xq, ww, bias, out);
  } else {
    hipLaunchKernelGGL(conv_naive, dim3(131072), dim3(256), 0, stream, x, w, bias, out);
  }
}